// Round 1
// 485.069 us; speedup vs baseline: 1.3800x; 1.3800x over previous
//
#include <hip/hip_runtime.h>
#include <hip/hip_bf16.h>
#include <math.h>

// Problem constants (from reference): B=4, T=4096, D=1024, hidden=4D.
#define B_SZ 4
#define T_SZ 4096
#define D_SZ 1024
#define H_SZ 4096
#define CHUNK 16
#define NCHUNK (T_SZ / CHUNK)   // 256
#define LN_EPS 1e-5f

using frag8 = __attribute__((ext_vector_type(8))) short;   // 8 x bf16 (4 VGPRs)
using f32x4 = __attribute__((ext_vector_type(4))) float;   // 4 x f32 acc

__device__ __forceinline__ float gelu_exact(float x) {
  return 0.5f * x * (1.0f + erff(x * 0.70710678118654752f));
}

// tanh-form gelu: x*sigmoid(2u) = x - x/(e^{2u}+1), overflow-safe.
__device__ __forceinline__ float gelu_fast(float x) {
  float u2 = 1.5957691216057308f * (x + 0.044715f * x * x * x);
  float e = __expf(u2);
  return x - x * __builtin_amdgcn_rcpf(e + 1.0f);
}

__device__ __forceinline__ unsigned short f2bf(float f) {
  unsigned u = __float_as_uint(f);
  u += 0x7fffu + ((u >> 16) & 1u);   // round-to-nearest-even
  return (unsigned short)(u >> 16);
}

// ---------------------------------------------------------------------------
// LN1 statistics: one block per (b,t) row; fused sum+sumsq reduction.
// ---------------------------------------------------------------------------
__global__ __launch_bounds__(256) void ln_stats(
    const float* __restrict__ x, float2* __restrict__ stats) {
  __shared__ float red[8];
  int tid = threadIdx.x;
  size_t row = (size_t)blockIdx.x * D_SZ;
  float4 v = ((const float4*)(x + row))[tid];
  float s = v.x + v.y + v.z + v.w;
  float q = v.x * v.x + v.y * v.y + v.z * v.z + v.w * v.w;
#pragma unroll
  for (int o = 32; o > 0; o >>= 1) {
    s += __shfl_xor(s, o, 64);
    q += __shfl_xor(q, o, 64);
  }
  int w = tid >> 6;
  if ((tid & 63) == 0) { red[w * 2] = s; red[w * 2 + 1] = q; }
  __syncthreads();
  if (tid == 0) {
    s = red[0] + red[2] + red[4] + red[6];
    q = red[1] + red[3] + red[5] + red[7];
    float mu = s * (1.0f / D_SZ);
    float var = q * (1.0f / D_SZ) - mu * mu;
    float2 st; st.x = mu; st.y = rsqrtf(var + LN_EPS);
    stats[blockIdx.x] = st;
  }
}

// ---------------------------------------------------------------------------
// Kernel A: per (b, time-chunk): LN1(from stats) + gelu + in-chunk cumsum.
// ---------------------------------------------------------------------------
__global__ __launch_bounds__(256) void attn_phase1(
    const float* __restrict__ x, const float2* __restrict__ stats,
    const int* __restrict__ lengths, const float* __restrict__ w1,
    float* __restrict__ partial, float* __restrict__ csum) {
  int b = blockIdx.x >> 8;          // NCHUNK = 256
  int c = blockIdx.x & (NCHUNK - 1);
  int tid = threadIdx.x;
  int len = lengths[b];
  float4 w = ((const float4*)w1)[tid];
  float run0 = 0.f, run1 = 0.f, run2 = 0.f, run3 = 0.f;
#pragma unroll 4
  for (int i = 0; i < CHUNK; ++i) {
    int t = c * CHUNK + i;
    size_t row = ((size_t)b * T_SZ + t) * D_SZ;
    float4 v = ((const float4*)(x + row))[tid];
    float2 st = stats[b * T_SZ + t];
    bool valid = t < len;
    float hx = (v.x - st.x) * st.y * w.x, hy = (v.y - st.x) * st.y * w.y;
    float hz = (v.z - st.x) * st.y * w.z, hw = (v.w - st.x) * st.y * w.w;
    if (valid) {
      run0 += gelu_exact(hx); run1 += gelu_exact(hy);
      run2 += gelu_exact(hz); run3 += gelu_exact(hw);
    }
    float4 p;
    p.x = v.x + hx + (valid ? run0 : 0.f);
    p.y = v.y + hy + (valid ? run1 : 0.f);
    p.z = v.z + hz + (valid ? run2 : 0.f);
    p.w = v.w + hw + (valid ? run3 : 0.f);
    ((float4*)(partial + row))[tid] = p;
  }
  float4 cs; cs.x = run0; cs.y = run1; cs.z = run2; cs.w = run3;
  ((float4*)(csum + ((size_t)b * NCHUNK + c) * D_SZ))[tid] = cs;
}

// ---------------------------------------------------------------------------
// Kernel B: in-place exclusive scan of chunk sums along c, per (b,d).
// ---------------------------------------------------------------------------
__global__ __launch_bounds__(256) void chunk_scan(float* __restrict__ csum) {
  int idx = blockIdx.x * 256 + threadIdx.x;   // 0 .. B*D-1
  int b = idx >> 10;
  int d = idx & (D_SZ - 1);
  float* p = csum + (size_t)b * NCHUNK * D_SZ + d;
  float acc = 0.f;
#pragma unroll 8
  for (int c = 0; c < NCHUNK; ++c) {
    float t = p[(size_t)c * D_SZ];
    p[(size_t)c * D_SZ] = acc;
    acc += t;
  }
}

// ---------------------------------------------------------------------------
// Kernel C: xres = partial + valid*offset (in place), then LN2 -> h2 (bf16).
// ---------------------------------------------------------------------------
__global__ __launch_bounds__(256) void attn_phase2_ln2(
    float* __restrict__ xres, const float* __restrict__ csum,
    const int* __restrict__ lengths, const float* __restrict__ w2,
    unsigned short* __restrict__ h2) {
  __shared__ float red[8];
  int t = blockIdx.x & (T_SZ - 1);
  int b = blockIdx.x >> 12;
  int tid = threadIdx.x;
  bool valid = t < lengths[b];
  int c = t / CHUNK;
  size_t row = ((size_t)b * T_SZ + t) * D_SZ;
  float4 v = ((const float4*)(xres + row))[tid];
  if (valid) {
    float4 o = ((const float4*)(csum + ((size_t)b * NCHUNK + c) * D_SZ))[tid];
    v.x += o.x; v.y += o.y; v.z += o.z; v.w += o.w;
  }
  ((float4*)(xres + row))[tid] = v;
  float s = v.x + v.y + v.z + v.w;
  float q = v.x * v.x + v.y * v.y + v.z * v.z + v.w * v.w;
#pragma unroll
  for (int o = 32; o > 0; o >>= 1) {
    s += __shfl_xor(s, o, 64);
    q += __shfl_xor(q, o, 64);
  }
  int wv = tid >> 6;
  if ((tid & 63) == 0) { red[wv * 2] = s; red[wv * 2 + 1] = q; }
  __syncthreads();
  s = red[0] + red[2] + red[4] + red[6];
  q = red[1] + red[3] + red[5] + red[7];
  float mu = s * (1.0f / D_SZ);
  float var = q * (1.0f / D_SZ) - mu * mu;
  float rstd = rsqrtf(var + LN_EPS);
  float4 w = ((const float4*)w2)[tid];
  ushort4 hq;
  hq.x = f2bf((v.x - mu) * rstd * w.x);
  hq.y = f2bf((v.y - mu) * rstd * w.y);
  hq.z = f2bf((v.z - mu) * rstd * w.z);
  hq.w = f2bf((v.w - mu) * rstd * w.w);
  ((ushort4*)(h2 + row))[tid] = hq;
}

// ---------------------------------------------------------------------------
// Transpose + fp32->bf16 convert: src (R x C) row-major -> dst (C x R) bf16.
// ---------------------------------------------------------------------------
__global__ __launch_bounds__(256) void transpose_f32_to_bf16(
    const float* __restrict__ src, unsigned short* __restrict__ dst,
    int R, int C) {
  __shared__ float tile[32][33];
  int bx = blockIdx.x * 32;   // C base
  int by = blockIdx.y * 32;   // R base
  int tx = threadIdx.x & 31;
  int ty = threadIdx.x >> 5;  // 0..7
#pragma unroll
  for (int i = 0; i < 32; i += 8)
    tile[ty + i][tx] = src[(size_t)(by + ty + i) * C + bx + tx];
  __syncthreads();
#pragma unroll
  for (int i = 0; i < 32; i += 8)
    dst[(size_t)(bx + ty + i) * R + by + tx] = f2bf(tile[tx][ty + i]);
}

// ---------------------------------------------------------------------------
// 256x256 8-phase bf16 GEMM (T1+T2+T3/T4+T5 template).
//   C[rows,N] = A[rows,K] * Bt[N,K]^T
//   512 threads = 8 waves (2M x 4N); wave tile 128x64; BK=64; nt = K/64.
//   LDS: 128 KiB dynamic = dbuf x (A 256x64 + B 256x64) bf16.
//   T2 swizzle: 16B chunk index ^= (row&7); applied inverse on the GLOBAL
//   source of global_load_lds (linear LDS dest) and forward on ds_read.
// ---------------------------------------------------------------------------
__device__ __forceinline__ void gld_lds16(const unsigned short* g,
                                          unsigned short* l) {
  __builtin_amdgcn_global_load_lds(
      (const __attribute__((address_space(1))) unsigned int*)g,
      (__attribute__((address_space(3))) unsigned int*)l, 16, 0, 0);
}

#define GT_TILE (256 * 64)   // ushorts per LDS tile buffer (32 KiB)

// A half-tile h: LDS rows {h*64..h*64+63} U {128+h*64..128+h*64+63}.
__device__ __forceinline__ void stageA(const unsigned short* A_blk, int K,
                                       unsigned short* as_buf, int h, int k0,
                                       int tid) {
#pragma unroll
  for (int j = 0; j < 2; ++j) {
    int R = j * 128 + h * 64 + (tid >> 3);            // LDS/tile row
    int kc = ((tid & 7) * 8) ^ ((R & 7) << 3);        // inverse-swizzled src k
    gld_lds16(A_blk + (size_t)R * K + k0 + kc,
              as_buf + R * 64 + (tid & 7) * 8);       // linear dest
  }
}

// B half-tile h: LDS rows {0,64,128,192}+h*32 .. +31.
__device__ __forceinline__ void stageB(const unsigned short* B_blk, int K,
                                       unsigned short* bs_buf, int h, int k0,
                                       int tid) {
  int lr = tid >> 3;   // 0..63
#pragma unroll
  for (int j = 0; j < 2; ++j) {
    int R = j * 128 + (lr >> 5) * 64 + h * 32 + (lr & 31);
    int kc = ((tid & 7) * 8) ^ ((R & 7) << 3);
    gld_lds16(B_blk + (size_t)R * K + k0 + kc,
              bs_buf + R * 64 + (tid & 7) * 8);
  }
}

template <int MH>
__device__ __forceinline__ void load_a(const unsigned short* As_c,
                                       frag8 (&af)[4][2], int wm, int r16,
                                       int quad) {
#pragma unroll
  for (int tm = 0; tm < 4; ++tm)
#pragma unroll
    for (int kk = 0; kk < 2; ++kk) {
      int r = wm * 128 + MH * 64 + tm * 16 + r16;
      int cb = (kk * 64 + quad * 16) ^ ((r16 & 7) << 4);   // swizzled byte col
      af[tm][kk] = *(const frag8*)(As_c + r * 64 + (cb >> 1));
    }
}

template <int NH>
__device__ __forceinline__ void load_b(const unsigned short* Bs_c,
                                       frag8 (&bfr)[2][2][2], int wn, int r16,
                                       int quad) {
#pragma unroll
  for (int tn = 0; tn < 2; ++tn)
#pragma unroll
    for (int kk = 0; kk < 2; ++kk) {
      int r = wn * 64 + NH * 32 + tn * 16 + r16;
      int cb = (kk * 64 + quad * 16) ^ ((r16 & 7) << 4);
      bfr[NH][tn][kk] = *(const frag8*)(Bs_c + r * 64 + (cb >> 1));
    }
}

template <int MH, int NH>
__device__ __forceinline__ void mfma_q(f32x4 (&acc)[8][4],
                                       const frag8 (&af)[4][2],
                                       const frag8 (&bfr)[2][2][2]) {
#pragma unroll
  for (int kk = 0; kk < 2; ++kk)
#pragma unroll
    for (int tm = 0; tm < 4; ++tm)
#pragma unroll
      for (int tn = 0; tn < 2; ++tn)
        acc[MH * 4 + tm][NH * 2 + tn] =
            __builtin_amdgcn_mfma_f32_16x16x32_bf16(
                af[tm][kk], bfr[NH][tn][kk], acc[MH * 4 + tm][NH * 2 + tn],
                0, 0, 0);
}

// Raw barrier (no implicit vmcnt drain) + compiler memory fence both sides.
#define GBAR()                          \
  do {                                  \
    asm volatile("" ::: "memory");      \
    __builtin_amdgcn_s_barrier();       \
    asm volatile("" ::: "memory");      \
  } while (0)

__global__ __launch_bounds__(512, 2) void gemm256_bt(
    const unsigned short* __restrict__ A, const unsigned short* __restrict__ Bt,
    int N, int K, int gx,
    const float* __restrict__ resid, float* __restrict__ outf,
    unsigned short* __restrict__ outb, int epi) {
  extern __shared__ unsigned short smem[];
  unsigned short* As = smem;                 // [2][256][64]
  unsigned short* Bs = smem + 2 * GT_TILE;   // [2][256][64]

  // XCD-aware bijective block swizzle (grid % 8 == 0 in our launches).
  int orig = blockIdx.x, nwg = gridDim.x;
  int wg = orig;
  if ((nwg & 7) == 0) wg = (orig & 7) * (nwg >> 3) + (orig >> 3);
  int bx = wg % gx, by = wg / gx;
  int bm = by * 256, bn = bx * 256;

  int tid = threadIdx.x;
  int lane = tid & 63, wave = tid >> 6;
  int wm = wave >> 2, wn = wave & 3;         // 2 x 4 wave grid
  int quad = lane >> 4, r16 = lane & 15;

  const unsigned short* A_blk = A + (size_t)bm * K;
  const unsigned short* B_blk = Bt + (size_t)bn * K;
  int nt = K >> 6;

  f32x4 acc[8][4] = {};
  frag8 af[4][2];          // current m-half fragments
  frag8 bfr[2][2][2];      // both n-half fragments (register-resident per tile)

  // Prologue: tile 0 full (8 loads) + tile 1 A0,B0,B1 (6 loads); wait oldest 8.
  stageA(A_blk, K, As, 0, 0, tid);
  stageA(A_blk, K, As, 1, 0, tid);
  stageB(B_blk, K, Bs, 0, 0, tid);
  stageB(B_blk, K, Bs, 1, 0, tid);
  if (nt > 1) {
    stageA(A_blk, K, As + GT_TILE, 0, 64, tid);
    stageB(B_blk, K, Bs + GT_TILE, 0, 64, tid);
    stageB(B_blk, K, Bs + GT_TILE, 1, 64, tid);
    asm volatile("s_waitcnt vmcnt(6)" ::: "memory");
  } else {
    asm volatile("s_waitcnt vmcnt(0)" ::: "memory");
  }
  GBAR();

  // Main loop. Per tile: 4 phases in Gray order (A0B0, A0B1, A1B1, A1B0).
  // Each phase stages one half-tile whose LDS region is provably dead.
  // One counted vmcnt(6) per tile (3 half-tiles stay in flight).
  for (int t = 0; t < nt; ++t) {
    unsigned short* As_c = As + (t & 1) * GT_TILE;
    unsigned short* Bs_c = Bs + (t & 1) * GT_TILE;
    unsigned short* As_n = As + ((t + 1) & 1) * GT_TILE;
    bool p1 = (t + 1 < nt), p2 = (t + 2 < nt);

    // ---- phase 0: compute (A0,B0); stage (t+1, A1) -> other buffer.
    load_a<0>(As_c, af, wm, r16, quad);
    load_b<0>(Bs_c, bfr, wn, r16, quad);
    if (p1) stageA(A_blk, K, As_n, 1, (t + 1) * 64, tid);
    asm volatile("s_waitcnt lgkmcnt(8)" ::: "memory");
    GBAR();
    asm volatile("s_waitcnt lgkmcnt(0)" ::: "memory");
    __builtin_amdgcn_s_setprio(1);
    mfma_q<0, 0>(acc, af, bfr);
    __builtin_amdgcn_s_setprio(0);
    GBAR();

    // ---- phase 1: compute (A0,B1); stage (t+2, A0) -> current buffer
    //      (A0 region dead: consumed into regs at phase 0, all waves past bar).
    load_b<1>(Bs_c, bfr, wn, r16, quad);
    if (p2) stageA(A_blk, K, As_c, 0, (t + 2) * 64, tid);
    GBAR();
    asm volatile("s_waitcnt lgkmcnt(0)" ::: "memory");
    __builtin_amdgcn_s_setprio(1);
    mfma_q<0, 1>(acc, af, bfr);
    __builtin_amdgcn_s_setprio(0);
    GBAR();

    // ---- phase 2: compute (A1,B1); stage (t+2, B0) (dead since phase 0).
    load_a<1>(As_c, af, wm, r16, quad);
    if (p2) stageB(B_blk, K, Bs_c, 0, (t + 2) * 64, tid);
    GBAR();
    asm volatile("s_waitcnt lgkmcnt(0)" ::: "memory");
    __builtin_amdgcn_s_setprio(1);
    mfma_q<1, 1>(acc, af, bfr);
    __builtin_amdgcn_s_setprio(0);
    GBAR();

    // ---- phase 3: compute (A1,B0) from regs; stage (t+2, B1) (dead since
    //      phase 1); counted vmcnt completes tile t+1, leaves 6 in flight.
    if (p2) {
      stageB(B_blk, K, Bs_c, 1, (t + 2) * 64, tid);
      asm volatile("s_waitcnt vmcnt(6)" ::: "memory");
    } else {
      asm volatile("s_waitcnt vmcnt(0)" ::: "memory");
    }
    GBAR();
    __builtin_amdgcn_s_setprio(1);
    mfma_q<1, 0>(acc, af, bfr);
    __builtin_amdgcn_s_setprio(0);
    GBAR();
  }

  // Epilogue. C row = bm + wm*128 + mf*16 + quad*4 + r; col = bn + wn*64 +
  // nf*16 + r16 (C/D layout: col=lane&15, row=(lane>>4)*4+reg).
  if (epi == 0) {
#pragma unroll
    for (int mf = 0; mf < 8; ++mf) {
#pragma unroll
      for (int nf = 0; nf < 4; ++nf) {
        int gm0 = bm + wm * 128 + mf * 16 + quad * 4;
        int gn = bn + wn * 64 + nf * 16 + r16;
#pragma unroll
        for (int r = 0; r < 4; ++r)
          outb[(size_t)(gm0 + r) * N + gn] = f2bf(gelu_fast(acc[mf][nf][r]));
      }
    }
  } else {
#pragma unroll
    for (int mf = 0; mf < 8; ++mf) {
#pragma unroll
      for (int nf = 0; nf < 4; ++nf) {
        int gm0 = bm + wm * 128 + mf * 16 + quad * 4;
        int gn = bn + wn * 64 + nf * 16 + r16;
#pragma unroll
        for (int r = 0; r < 4; ++r)
          outf[(size_t)(gm0 + r) * N + gn] =
              resid[(size_t)(gm0 + r) * N + gn] + acc[mf][nf][r];
      }
    }
  }
}

// ---------------------------------------------------------------------------
extern "C" void kernel_launch(void* const* d_in, const int* in_sizes, int n_in,
                              void* d_out, int out_size, void* d_ws,
                              size_t ws_size, hipStream_t stream) {
  const float* x = (const float*)d_in[0];
  const int* lengths = (const int*)d_in[1];
  const float* ln1_w = (const float*)d_in[2];
  const float* ln2_w = (const float*)d_in[3];
  const float* Wfc = (const float*)d_in[4];
  const float* Wproj = (const float*)d_in[5];
  float* out = (float*)d_out;   // doubles as the xres residual-stream buffer

  // One-time: allow 128 KiB dynamic LDS for the 256^2 GEMM.
  static bool lds_cfg = false;
  if (!lds_cfg) {
    hipFuncSetAttribute((const void*)gemm256_bt,
                        hipFuncAttributeMaxDynamicSharedMemorySize, 131072);
    lds_cfg = true;
  }

  // Workspace layout — fixed ~52 MiB + act slice sized from ws_size.
  char* ws = (char*)d_ws;
  size_t off = 0;
  float2* stats = (float2*)(ws + off);
  off += (size_t)B_SZ * T_SZ * sizeof(float2);                  // 128 KiB
  float* csum = (float*)(ws + off);
  off += (size_t)B_SZ * NCHUNK * D_SZ * sizeof(float);          // 4 MiB
  unsigned short* wfcb = (unsigned short*)(ws + off);
  off += (size_t)D_SZ * H_SZ * sizeof(unsigned short);          // 8 MiB
  unsigned short* wprojb = (unsigned short*)(ws + off);
  off += (size_t)H_SZ * D_SZ * sizeof(unsigned short);          // 8 MiB
  unsigned short* h2 = (unsigned short*)(ws + off);
  off += (size_t)B_SZ * T_SZ * D_SZ * sizeof(unsigned short);   // 32 MiB
  unsigned short* act = (unsigned short*)(ws + off);            // slice buffer

  const int M = B_SZ * T_SZ;                       // 16384
  const size_t tileBytes = 256ull * H_SZ * sizeof(unsigned short);  // 2 MiB
  size_t avail = (ws_size > off) ? (ws_size - off) : 0;
  int sliceTiles = (int)(avail / tileBytes);
  if (sliceTiles < 1) sliceTiles = 1;              // last-resort (ws too small)
  int sliceM = sliceTiles * 256;
  if (sliceM > M) sliceM = M;

  ln_stats<<<B_SZ * T_SZ, 256, 0, stream>>>(x, stats);
  attn_phase1<<<B_SZ * NCHUNK, 256, 0, stream>>>(x, stats, lengths, ln1_w,
                                                 out, csum);
  chunk_scan<<<(B_SZ * D_SZ) / 256, 256, 0, stream>>>(csum);
  attn_phase2_ln2<<<B_SZ * T_SZ, 256, 0, stream>>>(out, csum, lengths, ln2_w, h2);
  transpose_f32_to_bf16<<<dim3(H_SZ / 32, D_SZ / 32), 256, 0, stream>>>(
      Wfc, wfcb, D_SZ, H_SZ);
  transpose_f32_to_bf16<<<dim3(D_SZ / 32, H_SZ / 32), 256, 0, stream>>>(
      Wproj, wprojb, H_SZ, D_SZ);

  for (int m0 = 0; m0 < M; m0 += sliceM) {
    int rows = (M - m0 < sliceM) ? (M - m0) : sliceM;
    int r1 = rows / 256;
    // act = bf16(gelu(h2[m0:m0+rows] @ Wfc))       grid = 16*r1 (%8==0)
    gemm256_bt<<<dim3((H_SZ / 256) * r1), 512, 131072, stream>>>(
        h2 + (size_t)m0 * D_SZ, wfcb, H_SZ, D_SZ, H_SZ / 256,
        nullptr, nullptr, act, 0);
    // out[m0:m0+rows] += act @ Wproj               grid = 4*r1
    gemm256_bt<<<dim3((D_SZ / 256) * r1), 512, 131072, stream>>>(
        act, wprojb, D_SZ, H_SZ, D_SZ / 256,
        out + (size_t)m0 * D_SZ, out + (size_t)m0 * D_SZ, nullptr, 1);
  }
}